// Round 3
// baseline (204.794 us; speedup 1.0000x reference)
//
#include <hip/hip_runtime.h>
#include <stdint.h>

// Problem constants: N=128, T=2048, D=88
#define NN 128
#define TT 2048
#define DD 88
#define ROWS 32                        // timesteps per tile
#define F4_ROW 22                      // float4 per row (88 floats)
#define TILES (NN * TT / ROWS)         // 8192 tiles total
#define TILES_PER_BLK 4
#define K1_GRID (TILES / TILES_PER_BLK)  // 2048 blocks (256 CU x 8)
#define PARTS_PER_N 256                // per-wave tp partials per n (64 tiles x 4 waves)
#define CPN 8                          // tail chunk-blocks per n
#define K2_BLOCKS (NN * CPN)           // 1024

typedef float f4 __attribute__((ext_vector_type(4)));

// K1 v3 (persistent + pipelined): R1 (LDS-staged) and R2 (direct-to-reg)
// both measured 66.5 us at 2.8 TB/s SQ-side read BW, and the L3-resident
// rocprof replay (FETCH=1.3MB) was ALSO 66 us -> the limit is the on-die
// read fabric, not HBM. Last structural suspect before declaring roofline:
// block churn (8192 one-shot blocks, waves spend life ramping in/out,
// occupancy 64% despite no resource cap). This version: 2048 blocks x 4
// tiles, 2-deep software pipeline (next tile's 6 loads issued before
// current tile's compute), zero barriers / zero LDS (tp partials written
// per-wave; K2's 256 threads absorb the wider reduction for free).
__global__ __launch_bounds__(256) void acc_rowstats_kernel(
    const float* __restrict__ outp, const float* __restrict__ tgt,
    float* __restrict__ fpfn, float* __restrict__ tp_part) {
  const int tid = threadIdx.x;
  const int lane = tid & 63;
  const int wave = tid >> 6;
  const int r = tid >> 3;            // 0..31 : row within tile
  const int s = tid & 7;             // 0..7  : f4 slot group within row
  const int j2 = (s < 6) ? (s + 16) : s;  // 3rd slot; s>=6 re-reads (L1 hit), masked
  const int tile0 = blockIdx.x * TILES_PER_BLK;

  const f4* __restrict__ ob = (const f4*)outp;
  const f4* __restrict__ gb = (const f4*)tgt;

#define LOADT(T, oA, gA, oB, gB, oC, gC)              \
  do {                                                \
    const size_t ro = ((size_t)(T) * ROWS + r) * F4_ROW; \
    oA = ob[ro + s];      gA = gb[ro + s];            \
    oB = ob[ro + s + 8];  gB = gb[ro + s + 8];        \
    oC = ob[ro + j2];     gC = gb[ro + j2];           \
  } while (0)

#define ACC1(ov, gv, xa, ta)                          \
  do {                                                \
    const float pf = ((ov) > 0.f) ? 1.f : 0.f;        \
    (xa) += fabsf(pf - (gv));                         \
    (ta) = fmaf(pf, (gv), (ta));                      \
  } while (0)

#define COMPT(T, oA, gA, oB, gB, oC, gC)                                   \
  do {                                                                     \
    float x = 0.f, tp = 0.f, x2 = 0.f, tp2 = 0.f;                          \
    ACC1(oA.x, gA.x, x, tp);   ACC1(oA.y, gA.y, x, tp);                    \
    ACC1(oA.z, gA.z, x, tp);   ACC1(oA.w, gA.w, x, tp);                    \
    ACC1(oB.x, gB.x, x, tp);   ACC1(oB.y, gB.y, x, tp);                    \
    ACC1(oB.z, gB.z, x, tp);   ACC1(oB.w, gB.w, x, tp);                    \
    ACC1(oC.x, gC.x, x2, tp2); ACC1(oC.y, gC.y, x2, tp2);                  \
    ACC1(oC.z, gC.z, x2, tp2); ACC1(oC.w, gC.w, x2, tp2);                  \
    if (s < 6) { x += x2; tp += tp2; }                                     \
    x += __shfl_down(x, 4, 64);                                            \
    x += __shfl_down(x, 2, 64);                                            \
    x += __shfl_down(x, 1, 64);                                            \
    if (s == 0) fpfn[(size_t)(T)*ROWS + r] = x;                            \
    for (int off = 32; off > 0; off >>= 1) tp += __shfl_down(tp, off, 64); \
    if (lane == 0) tp_part[(size_t)(T)*4 + wave] = tp;                     \
  } while (0)

  f4 oA0, gA0, oB0, gB0, oC0, gC0;  // pipeline buffer 0
  f4 oA1, gA1, oB1, gB1, oC1, gC1;  // pipeline buffer 1

  LOADT(tile0 + 0, oA0, gA0, oB0, gB0, oC0, gC0);
  LOADT(tile0 + 1, oA1, gA1, oB1, gB1, oC1, gC1);
  COMPT(tile0 + 0, oA0, gA0, oB0, gB0, oC0, gC0);
  LOADT(tile0 + 2, oA0, gA0, oB0, gB0, oC0, gC0);
  COMPT(tile0 + 1, oA1, gA1, oB1, gB1, oC1, gC1);
  LOADT(tile0 + 3, oA1, gA1, oB1, gB1, oC1, gC1);
  COMPT(tile0 + 2, oA0, gA0, oB0, gB0, oC0, gC0);
  COMPT(tile0 + 3, oA1, gA1, oB1, gB1, oC1, gC1);

#undef LOADT
#undef ACC1
#undef COMPT
}

// K2: 8 chunk-blocks per n; all global loads issue before any reduction;
// Ti/tp are exact-integer sums (order-insensitive); 2 barriers; no atomics.
// Only change: tp partials are now per-wave (256 per n), so every thread
// loads one -- the reduction tree is identical, still bit-exact.
__global__ __launch_bounds__(256) void acc_chunk_kernel(
    const int* __restrict__ mask, const float* __restrict__ fpfn,
    const float* __restrict__ tp_part, float* __restrict__ accp) {
  const int b = blockIdx.x;
  const int n = b >> 3;            // CPN = 8
  const int c = b & (CPN - 1);
  const int tid = threadIdx.x;
  const int lane = tid & 63;
  const int wave = tid >> 6;
  __shared__ float s_ti[4];
  __shared__ float s_tp[4];
  __shared__ float s_a[4];

  // ---- issue every global load up front (nothing gated on reductions) ----
  const int4* m4 = (const int4*)(mask + (size_t)n * TT);
  const int4 v0 = m4[tid];
  const int4 v1 = m4[tid + 256];
  const float tpv = tp_part[n * PARTS_PER_N + tid];
  const int t = c * 256 + tid;
  const float fr = fpfn[(size_t)n * TT + t];

  // ---- Ti and tp: exact-integer shuffle reductions (order-insensitive) ----
  int ti = v0.x + v0.y + v0.z + v0.w + v1.x + v1.y + v1.z + v1.w;
  float tp = tpv;
  for (int off = 32; off > 0; off >>= 1) {
    ti += __shfl_down(ti, off, 64);
    tp += __shfl_down(tp, off, 64);
  }
  if (lane == 0) { s_ti[wave] = (float)ti; s_tp[wave] = tp; }
  __syncthreads();
  const float fTi = s_ti[0] + s_ti[1] + s_ti[2] + s_ti[3];  // exact (<= 2048)
  const float tpn = s_tp[0] + s_tp[1] + s_tp[2] + s_tp[3];  // exact integer
  const int Ti = (int)fTi;

  // ---- ratio for this block's 256 timesteps, then block reduction ----
  float a = (t < Ti) ? tpn / (tpn + fr) : 0.f;
  for (int off = 32; off > 0; off >>= 1) a += __shfl_down(a, off, 64);
  if (lane == 0) s_a[wave] = a;
  __syncthreads();
  if (tid == 0)
    accp[b] = (s_a[0] + s_a[1] + s_a[2] + s_a[3]) / fTi;
}

// K3: deterministic final sum of the 1024 chunk partials -> out[0].
__global__ __launch_bounds__(256) void acc_sum_kernel(
    const float* __restrict__ accp, float* __restrict__ out) {
  const int tid = threadIdx.x;
  const int lane = tid & 63;
  const int wave = tid >> 6;
  __shared__ float s_a[4];
  float a = accp[tid] + accp[tid + 256] + accp[tid + 512] + accp[tid + 768];
  for (int off = 32; off > 0; off >>= 1) a += __shfl_down(a, off, 64);
  if (lane == 0) s_a[wave] = a;
  __syncthreads();
  if (tid == 0) out[0] = s_a[0] + s_a[1] + s_a[2] + s_a[3];
}

extern "C" void kernel_launch(void* const* d_in, const int* in_sizes, int n_in,
                              void* d_out, int out_size, void* d_ws, size_t ws_size,
                              hipStream_t stream) {
  const float* output = (const float*)d_in[0];
  const float* target = (const float*)d_in[1];
  const int* mask = (const int*)d_in[2];
  float* out = (float*)d_out;

  float* tp_part = (float*)d_ws;                 // TILES*4 = 32768 floats
  float* fpfn = tp_part + (size_t)TILES * 4;     // N*T floats
  float* accp = fpfn + (size_t)NN * TT;          // K2_BLOCKS floats

  acc_rowstats_kernel<<<K1_GRID, 256, 0, stream>>>(output, target, fpfn, tp_part);
  acc_chunk_kernel<<<K2_BLOCKS, 256, 0, stream>>>(mask, fpfn, tp_part, accp);
  acc_sum_kernel<<<1, 256, 0, stream>>>(accp, out);
}

// Round 4
// 199.575 us; speedup vs baseline: 1.0262x; 1.0262x over previous
//
#include <hip/hip_runtime.h>
#include <stdint.h>

// Problem constants: N=128, T=2048, D=88
#define NN 128
#define TT 2048
#define DD 88
#define ROWS 32                      // timesteps per K1 block
#define F4_ROW 22                    // float4 per row (88 floats)
#define F4_TILE (ROWS * F4_ROW)      // 704 f4 = 11264 B per array
#define INSTR_PER_ARR 11             // 11 x 1KB global_load_lds per array
#define K1_BLOCKS (NN * TT / ROWS)   // 8192
#define PARTS_PER_N (TT / ROWS)      // 64 tp partials per n
#define CPN 8                        // tail chunk-blocks per n
#define K2_BLOCKS (NN * CPN)         // 1024

typedef float f4 __attribute__((ext_vector_type(4)));
typedef const __attribute__((address_space(1))) uint32_t guint;
typedef __attribute__((address_space(3))) uint32_t luint;

// K1: async global->LDS staging (no VGPR round-trip; all of a wave's 1KB
// loads in flight), then per-row fpfn + per-block tp partial.
// FINAL (reverted to best measured): 66.5 us = 184.6 MB / 2.80 TB/s =
// ~89% of the read-direction fabric ceiling (m13 copy: 3.15 TB/s/dir).
// Verified invariant across 8 structures (LDS-staged / direct-to-reg /
// persistent-pipelined; occupancy 51-64%; conflicts 0-1.3M; VALU 6-15%):
// all land 66-71 us -> chip-level L2-miss read-path wall, not structure.
__global__ __launch_bounds__(256) void acc_rowstats_kernel(
    const float* __restrict__ outp, const float* __restrict__ tgt,
    float* __restrict__ fpfn, float* __restrict__ tp_part) {
  __shared__ f4 lds_o[F4_TILE];
  __shared__ f4 lds_g[F4_TILE];
  __shared__ float s_tp[4];

  const int tid = threadIdx.x;
  const int lane = tid & 63;
  const int wave = tid >> 6;
  const int blk = blockIdx.x;
  const size_t tile_f = (size_t)blk * (ROWS * DD);  // element offset of tile

  // ---- stage 22 x 1KB direct-to-LDS (waves 0,1: 6 instrs; waves 2,3: 5) ----
  for (int j = wave; j < 2 * INSTR_PER_ARR; j += 4) {
    const int is_g = (j >= INSTR_PER_ARR) ? 1 : 0;
    const int idx = j - is_g * INSTR_PER_ARR;        // wave-uniform
    const float* src = (is_g ? tgt : outp) + tile_f + idx * 256;
    float* dst = (is_g ? (float*)lds_g : (float*)lds_o) + idx * 256;
    __builtin_amdgcn_global_load_lds((guint*)src + lane * 4, (luint*)dst,
                                     16, 0, 0);
  }
  __syncthreads();  // compiler drains vmcnt before the barrier

  // ---- consume from LDS: 8 threads per row ----
  const int r = tid >> 3;  // 0..31
  const int s = tid & 7;
  float tp = 0.f;
  float x = 0.f;
#pragma unroll
  for (int j0 = 0; j0 < 3; ++j0) {
    const int j = s + j0 * 8;
    if (j < F4_ROW) {
      const f4 o = lds_o[r * F4_ROW + j];
      const f4 g = lds_g[r * F4_ROW + j];
      {
        const float pf = (o.x > 0.f) ? 1.f : 0.f;
        x += fabsf(pf - g.x);
        tp = fmaf(pf, g.x, tp);
      }
      {
        const float pf = (o.y > 0.f) ? 1.f : 0.f;
        x += fabsf(pf - g.y);
        tp = fmaf(pf, g.y, tp);
      }
      {
        const float pf = (o.z > 0.f) ? 1.f : 0.f;
        x += fabsf(pf - g.z);
        tp = fmaf(pf, g.z, tp);
      }
      {
        const float pf = (o.w > 0.f) ? 1.f : 0.f;
        x += fabsf(pf - g.w);
        tp = fmaf(pf, g.w, tp);
      }
    }
  }
  // fpfn: reduce across the 8 contiguous lanes of this row
  x += __shfl_down(x, 4, 64);
  x += __shfl_down(x, 2, 64);
  x += __shfl_down(x, 1, 64);
  if (s == 0) fpfn[(size_t)blk * ROWS + r] = x;

  // tp: wave reduce + cross-wave, deterministic per-block partial
  for (int off = 32; off > 0; off >>= 1) tp += __shfl_down(tp, off, 64);
  if (lane == 0) s_tp[wave] = tp;
  __syncthreads();
  if (tid == 0) tp_part[blk] = s_tp[0] + s_tp[1] + s_tp[2] + s_tp[3];
}

// K2: 8 chunk-blocks per n; all global loads issue before any reduction;
// Ti/tp are exact-integer sums (order-insensitive); 2 barriers; no atomics.
__global__ __launch_bounds__(256) void acc_chunk_kernel(
    const int* __restrict__ mask, const float* __restrict__ fpfn,
    const float* __restrict__ tp_part, float* __restrict__ accp) {
  const int b = blockIdx.x;
  const int n = b >> 3;            // CPN = 8
  const int c = b & (CPN - 1);
  const int tid = threadIdx.x;
  const int lane = tid & 63;
  const int wave = tid >> 6;
  __shared__ float s_ti[4];
  __shared__ float s_tp[4];
  __shared__ float s_a[4];

  // ---- issue every global load up front (nothing gated on reductions) ----
  const int4* m4 = (const int4*)(mask + (size_t)n * TT);
  const int4 v0 = m4[tid];
  const int4 v1 = m4[tid + 256];
  const float tpv = (tid < PARTS_PER_N) ? tp_part[n * PARTS_PER_N + tid] : 0.f;
  const int t = c * 256 + tid;
  const float fr = fpfn[(size_t)n * TT + t];

  // ---- Ti and tp: exact-integer shuffle reductions (order-insensitive) ----
  int ti = v0.x + v0.y + v0.z + v0.w + v1.x + v1.y + v1.z + v1.w;
  float tp = tpv;
  for (int off = 32; off > 0; off >>= 1) {
    ti += __shfl_down(ti, off, 64);
    tp += __shfl_down(tp, off, 64);
  }
  if (lane == 0) { s_ti[wave] = (float)ti; s_tp[wave] = tp; }
  __syncthreads();
  const float fTi = s_ti[0] + s_ti[1] + s_ti[2] + s_ti[3];  // exact (<= 2048)
  const float tpn = s_tp[0] + s_tp[1] + s_tp[2] + s_tp[3];  // exact integer
  const int Ti = (int)fTi;

  // ---- ratio for this block's 256 timesteps, then block reduction ----
  float a = (t < Ti) ? tpn / (tpn + fr) : 0.f;
  for (int off = 32; off > 0; off >>= 1) a += __shfl_down(a, off, 64);
  if (lane == 0) s_a[wave] = a;
  __syncthreads();
  if (tid == 0)
    accp[b] = (s_a[0] + s_a[1] + s_a[2] + s_a[3]) / fTi;
}

// K3: deterministic final sum of the 1024 chunk partials -> out[0].
__global__ __launch_bounds__(256) void acc_sum_kernel(
    const float* __restrict__ accp, float* __restrict__ out) {
  const int tid = threadIdx.x;
  const int lane = tid & 63;
  const int wave = tid >> 6;
  __shared__ float s_a[4];
  float a = accp[tid] + accp[tid + 256] + accp[tid + 512] + accp[tid + 768];
  for (int off = 32; off > 0; off >>= 1) a += __shfl_down(a, off, 64);
  if (lane == 0) s_a[wave] = a;
  __syncthreads();
  if (tid == 0) out[0] = s_a[0] + s_a[1] + s_a[2] + s_a[3];
}

extern "C" void kernel_launch(void* const* d_in, const int* in_sizes, int n_in,
                              void* d_out, int out_size, void* d_ws, size_t ws_size,
                              hipStream_t stream) {
  const float* output = (const float*)d_in[0];
  const float* target = (const float*)d_in[1];
  const int* mask = (const int*)d_in[2];
  float* out = (float*)d_out;

  float* tp_part = (float*)d_ws;          // K1_BLOCKS floats
  float* fpfn = tp_part + K1_BLOCKS;      // N*T floats
  float* accp = fpfn + (size_t)NN * TT;   // K2_BLOCKS floats

  acc_rowstats_kernel<<<K1_BLOCKS, 256, 0, stream>>>(output, target, fpfn, tp_part);
  acc_chunk_kernel<<<K2_BLOCKS, 256, 0, stream>>>(mask, fpfn, tp_part, accp);
  acc_sum_kernel<<<1, 256, 0, stream>>>(accp, out);
}